// Round 15
// baseline (61.886 us; speedup 1.0000x reference)
//
#include <hip/hip_runtime.h>

// sPLL — bit-exact arithmetic (verified R11-R14). This round:
//  * 4-way time-split redundancy: 1024 blocks; role r computes t=[0,CS[r+1])
//    and stores t=[CS[r],CS[r+1]), CS={0,120,250,370,500}. Same recurrence,
//    same init => identical bits; 4 waves/SIMD fill dependency bubbles.
//  * trimmed step: V-1>0 replaced by V>1.0f (exact equivalence for finite V);
//    V-reset pair of cndmasks merged to one predicated select (same truth
//    table as the R14-verified form). ~27 VALU/step.
static constexpr int T  = 500;
static constexpr int BS = 256;
static constexpr int N  = 256;
static constexpr int U  = 10;                 // unroll; all CS multiples of U
static constexpr int R  = 4;                  // time-split roles
__constant__ __device__ const int CS[R + 1] = {0, 120, 250, 370, 500};

#define FPBAR(x) asm("" : "+v"(x))

struct Cell {
    float Vl, Il, crl, Vt, itrg, ifac, crt;
    bool  sp;
};

__device__ __forceinline__ void do_step(
    float x, float steady, Cell& c, float& sl_out, float& st_out)
{
    const float RC = 999.99993896484375f;   // f32(1/f32(0.001))

    // ---- LIF ----
    float u0 = c.Il * 0.8f;                      FPBAR(u0);
    float u1 = c.sp ? 1e-3f : 0.0f;                         // == 1e-3f*spk
    c.Il = u0 + u1;                              FPBAR(c.Il);
    float u3 = -c.Vl * 100.0f;                   FPBAR(u3);
    float u4 = c.Il + steady;                    FPBAR(u4);
    float u6 = __builtin_fmaf(u4, RC, u3);       FPBAR(u6);
    c.Vl = __builtin_fmaf(1e-3f, u6, c.Vl);      FPBAR(c.Vl);
    bool  bl  = c.Vl > 1.0f;                                // == (Vl-1>0)
    float crm = c.crl - 1.0f;                               // exact small ints
    bool  rg  = crm <= 0.0f;
    c.crl = bl ? 2.0f : crm;                                // == 2*spk+ns*(crl-1)
    c.Vl  = (!bl && rg) ? c.Vl : 0.0f;                      // == bl?0:(rg?Vl:0)
    sl_out = bl ? 1.0f : 0.0f;

    // ---- TDE ----
    float u13 = bl ? 1.0f : c.ifac;                         // == spk + ifac*ns
    c.ifac = u13 * 0.8f;                         FPBAR(c.ifac);
    float w0 = c.itrg * 0.9f;                    FPBAR(w0);
    float df  = c.ifac + c.ifac;                            // exact 2x
    float dfx = x * df;                          FPBAR(dfx);// exact (x in {0,1})
    bool  m1  = c.ifac > 0.1f;
    float pulse = m1 ? dfx : 0.0f;                          // == (x*2)*ifac*m1
    c.itrg = w0 + pulse;                         FPBAR(c.itrg);
    float u18 = -c.Vt * 100.0f;                  FPBAR(u18);
    float u20 = __builtin_fmaf(c.itrg, RC, u18); FPBAR(u20);
    c.Vt = __builtin_fmaf(1e-3f, u20, c.Vt);     FPBAR(c.Vt);
    bool  bt  = c.Vt > 1.0f;
    float ctm = c.crt - 1.0f;
    bool  rg2 = ctm <= 0.0f;
    c.crt = bt ? 2.0f : ctm;
    c.Vt  = (!bt && rg2) ? c.Vt : 0.0f;
    st_out = bt ? 1.0f : 0.0f;
    c.sp = bt;
}

template <bool STORE>
__device__ __forceinline__ void run_group(
    const float* __restrict__ s_inp, int g, float steady, Cell& c,
    float*& p0, float*& p1, size_t step)
{
    const float2 x01 = *reinterpret_cast<const float2*>(&s_inp[g * U + 0]);
    const float2 x23 = *reinterpret_cast<const float2*>(&s_inp[g * U + 2]);
    const float2 x45 = *reinterpret_cast<const float2*>(&s_inp[g * U + 4]);
    const float2 x67 = *reinterpret_cast<const float2*>(&s_inp[g * U + 6]);
    const float2 x89 = *reinterpret_cast<const float2*>(&s_inp[g * U + 8]);
    const float xs[U] = {x01.x, x01.y, x23.x, x23.y, x45.x,
                         x45.y, x67.x, x67.y, x89.x, x89.y};
    float sl, st;
#pragma unroll
    for (int j = 0; j < U; ++j) {
        do_step(xs[j], steady, c, sl, st);
        if (STORE) {
            p0[(size_t)j * step] = sl;
            p1[(size_t)j * step] = st;
        }
    }
    if (STORE) {
        p0 += (size_t)U * step;
        p1 += (size_t)U * step;
    }
}

__global__ __launch_bounds__(256, 4) void spll_kernel(
    const float* __restrict__ inp,      // (T, BS)
    const float* __restrict__ current,  // (N,)
    float* __restrict__ out)            // (2, T, BS, N)
{
#pragma clang fp contract(off)
    const int b    = blockIdx.x & (BS - 1);
    const int role = blockIdx.x >> 8;        // 0..R-1
    const int n    = threadIdx.x;

    __shared__ __align__(16) float s_inp[T];
    for (int i = threadIdx.x; i < T; i += blockDim.x)
        s_inp[i] = inp[i * BS + b];
    __syncthreads();

    const float steady = current[n];

    Cell c = {1.0f, 0.0f, 0.0f, 0.0f, 0.0f, 0.0f, 0.0f, false};

    const int gs = CS[role] / U;             // first stored group
    const int ge = CS[role + 1] / U;         // end group

    float* p0 = out + (size_t)b * N + n + (size_t)CS[role] * BS * N;
    float* p1 = p0 + (size_t)T * BS * N;
    const size_t step = (size_t)BS * N;      // 65536

    for (int g = 0; g < gs; ++g)
        run_group<false>(s_inp, g, steady, c, p0, p1, step);
    for (int g = gs; g < ge; ++g)
        run_group<true>(s_inp, g, steady, c, p0, p1, step);
}

extern "C" void kernel_launch(void* const* d_in, const int* in_sizes, int n_in,
                              void* d_out, int out_size, void* d_ws, size_t ws_size,
                              hipStream_t stream) {
    const float* a0 = (const float*)d_in[0];
    const float* a1 = (const float*)d_in[1];
    const float* inp = a0;
    const float* cur = a1;
    if (n_in >= 2 && in_sizes[0] == N && in_sizes[1] == T * BS) { inp = a1; cur = a0; }
    float* out = (float*)d_out;
    spll_kernel<<<dim3(R * BS), dim3(N), 0, stream>>>(inp, cur, out);
}